// Round 14
// baseline (241.597 us; speedup 1.0000x reference)
//
#include <hip/hip_runtime.h>
#include <stdint.h>

typedef int v4i __attribute__((ext_vector_type(4)));

#define K_DIM 4096
#define TPB_Q 256
#define BM 256
#define BN 256
#define BKB 128                     // K-bytes per tile
#define NT (K_DIM / BKB)            // 32 K-tiles
#define TILE_BYTES (256 * BKB)      // 32 KiB A tile

__device__ __forceinline__ void load_lds16(const void* g, void* l) {
  __builtin_amdgcn_global_load_lds(
      (const __attribute__((address_space(1))) void*)g,
      (__attribute__((address_space(3))) void*)l, 16, 0, 0);
}

// ---------------- per-row symmetric int8 quant (BW-bound, unchanged) --------
__global__ __launch_bounds__(TPB_Q) void quant_rows_kernel(
    const float* __restrict__ x, signed char* __restrict__ q,
    float* __restrict__ scales) {
  const int row = blockIdx.x;
  const float4* xr = (const float4*)(x + (size_t)row * K_DIM);
  float4 v[4];
  float m = 0.0f;
#pragma unroll
  for (int i = 0; i < 4; ++i) {
    v[i] = xr[threadIdx.x + i * TPB_Q];
    m = fmaxf(m, fmaxf(fmaxf(fabsf(v[i].x), fabsf(v[i].y)),
                       fmaxf(fabsf(v[i].z), fabsf(v[i].w))));
  }
#pragma unroll
  for (int off = 32; off > 0; off >>= 1) m = fmaxf(m, __shfl_down(m, off));
  __shared__ float red[TPB_Q / 64];
  if ((threadIdx.x & 63) == 0) red[threadIdx.x >> 6] = m;
  __syncthreads();
  m = fmaxf(fmaxf(red[0], red[1]), fmaxf(red[2], red[3]));
  const float scale = fmaxf(m / 127.0f, 1e-8f);
  if (threadIdx.x == 0) scales[row] = scale;
  uint32_t* qr = (uint32_t*)(q + (size_t)row * K_DIM);
#pragma unroll
  for (int i = 0; i < 4; ++i) {
    const float4 t = v[i];
    const int a0 = (int)fminf(fmaxf(rintf(t.x / scale), -128.0f), 127.0f);
    const int a1 = (int)fminf(fmaxf(rintf(t.y / scale), -128.0f), 127.0f);
    const int a2 = (int)fminf(fmaxf(rintf(t.z / scale), -128.0f), 127.0f);
    const int a3 = (int)fminf(fmaxf(rintf(t.w / scale), -128.0f), 127.0f);
    const uint32_t p = (uint32_t)(a0 & 255) | ((uint32_t)(a1 & 255) << 8) |
                       ((uint32_t)(a2 & 255) << 16) | ((uint32_t)(a3 & 255) << 24);
    qr[threadIdx.x + i * TPB_Q] = p;
  }
}

// ------- 256x256 i8 GEMM: A via LDS dbuf, B global->reg (end-prefetch) -----
// R8's free-run 1-barrier schedule; B removed from LDS entirely.
// 8 waves (wm 2 x wn 4); per-wave C 128x64 = acc[8][4] (128 AGPRs);
// a[8] (32 VGPR) + b[4][2] (32 VGPR) — b PREFETCHED AT END OF TILE (after
// its last MFMA use; in-order issue makes the reg WAR safe; R9's spill came
// from early prefetch doubling live sets).
// B global fragment: [N,K] row-major matches MFMA B layout 1:1 — lane reads
// 16B at row (wn*64+nj*16+l16), k = T*128 + ks*64 + lhi*16. b(T) issued one
// full tile early -> L2 latency fully hidden.
// vmem gate arithmetic (in-order counts): tile T sees issues
//   ... bpref(T)[8] | stage(T+1)[4] ... bpref(T+1)[8]
//   first MFMA cluster: vmcnt(4)  -> bpref(T) drained (stage(T+1) left)
//   boundary:           vmcnt(8)  -> stage(T+1) drained (bpref(T+1) left)
//   tails (no stage / no bpref): vmcnt(0).
// lgkm gates count only the 16 A ds_reads: 12/8/4/0 per pair-cluster.
// LDS: A-only double buffer 2 x 32 KiB = 64 KiB; 16B-chunk XOR swizzle
// (phys = logical ^ (row&7)); stage dest linear, source inverse-swizzled.
// XCD swizzle: grid 32r x 16c; XCD k owns rows[8*(k>>1),+8) x cols[8*(k&1),+8).
__global__ __launch_bounds__(512, 2) void gemm_i8_kernel(
    const signed char* __restrict__ qA, const signed char* __restrict__ qB,
    const float* __restrict__ sA, const float* __restrict__ sB,
    float* __restrict__ C, int M, int N, int K) {
  __shared__ __align__(16) signed char As[2 * TILE_BYTES];  // 64 KiB

  const int tid = threadIdx.x;
  const int wave = tid >> 6, lane = tid & 63;
  const int l16 = lane & 15, lhi = lane >> 4;
  const int wm = wave >> 2, wn = wave & 3;

  // XCD-chunked 2-D swizzle (bijective; 512 blocks, 8 XCDs, o%8 = XCD)
  const int o = blockIdx.x + blockIdx.y * gridDim.x;
  const int xcd = o & 7, slot = o >> 3;
  const int rb = ((xcd >> 1) << 3) + (slot >> 3);  // grid row 0..31
  const int cb = ((xcd & 1) << 3) + (slot & 7);    // grid col 0..15
  const int m0 = rb * BM, n0 = cb * BN;

  const signed char* Abase = qA + (size_t)m0 * K;
  const signed char* Bbase = qB + (size_t)n0 * K;

  // A staging: tile = 2048 x 16B chunks; thread d = s*512+tid, s=0..3.
  // dest linear (wave-uniform base + lane*16); source inverse-swizzled.
  int soff[4], sdst[4];
#pragma unroll
  for (int s = 0; s < 4; ++s) {
    const int d = s * 512 + tid;
    const int r = d >> 3;
    const int c = (d & 7) ^ (r & 7);
    soff[s] = r * K + c * 16;
    sdst[s] = s * 8192 + wave * 1024;
  }

#define STAGE_A(T_)                                                         \
  do {                                                                      \
    _Pragma("unroll") for (int s = 0; s < 4; ++s)                           \
        load_lds16(Abase + (size_t)(T_)*BKB + soff[s],                      \
                   As + ((T_)&1) * TILE_BYTES + sdst[s]);                   \
  } while (0)

  // swizzled A ds_read offsets (chunk = ks*4+lhi, row&7 = l16&7)
  int axor[2];
#pragma unroll
  for (int ks = 0; ks < 2; ++ks)
    axor[ks] = (((ks * 4 + lhi) ^ (l16 & 7)) << 4);
  const int aoff = wm * 16384 + l16 * 128;  // + mi*2048

  // B global fragment byte-offsets (per lane), + T*BKB per tile
  int bgo[4][2];
#pragma unroll
  for (int nj = 0; nj < 4; ++nj)
#pragma unroll
    for (int ks = 0; ks < 2; ++ks)
      bgo[nj][ks] = (wn * 64 + nj * 16 + l16) * K + ks * 64 + lhi * 16;

  const v4i vz = {0, 0, 0, 0};
  v4i acc[8][4];
#pragma unroll
  for (int i = 0; i < 8; ++i)
#pragma unroll
    for (int j = 0; j < 4; ++j) acc[i][j] = vz;

  v4i b[4][2];  // loop-carried; refilled at END of each tile (WAR-safe)

#define BPREF(T_)                                                            \
  do {                                                                       \
    const signed char* Bp_ = Bbase + (size_t)(T_)*BKB;                       \
    _Pragma("unroll") for (int nj = 0; nj < 4; ++nj)                         \
      _Pragma("unroll") for (int ks = 0; ks < 2; ++ks)                       \
          b[nj][ks] = *(const v4i*)(Bp_ + bgo[nj][ks]);                      \
  } while (0)

#define MFMA_PAIR(p0_, p1_)                                                  \
  do {                                                                       \
    _Pragma("unroll") for (int ks = 0; ks < 2; ++ks) {                       \
      _Pragma("unroll") for (int nj = 0; nj < 4; ++nj)                       \
          acc[p0_][nj] = __builtin_amdgcn_mfma_i32_16x16x64_i8(              \
              a[p0_], b[nj][ks], acc[p0_][nj], 0, 0, 0);                     \
    }                                                                        \
  } while (0)

// two mi rows x both ks halves, dependent acc reuse 8 instrs apart
#define MFMA_PAIR2(p0_, p1_)                                                 \
  do {                                                                       \
    _Pragma("unroll") for (int ks = 0; ks < 2; ++ks) {                       \
      _Pragma("unroll") for (int nj = 0; nj < 4; ++nj)                       \
          acc[p0_][nj] = __builtin_amdgcn_mfma_i32_16x16x64_i8(              \
              a2[p0_][ks], b[nj][ks], acc[p0_][nj], 0, 0, 0);                \
      _Pragma("unroll") for (int nj = 0; nj < 4; ++nj)                       \
          acc[p1_][nj] = __builtin_amdgcn_mfma_i32_16x16x64_i8(              \
              a2[p1_][ks], b[nj][ks], acc[p1_][nj], 0, 0, 0);                \
    }                                                                        \
  } while (0)

#define LGKM_GATE(n_)                                       \
  do {                                                      \
    asm volatile("s_waitcnt lgkmcnt(" #n_ ")" ::: "memory");\
    __builtin_amdgcn_sched_barrier(0);                      \
  } while (0)
#define VM_GATE(n_)                                         \
  do {                                                      \
    asm volatile("s_waitcnt vmcnt(" #n_ ")" ::: "memory");  \
    __builtin_amdgcn_sched_barrier(0);                      \
  } while (0)

  // prologue: stage A(0), prefetch b(0); drain all; sync.
  STAGE_A(0);
  BPREF(0);
  asm volatile("s_waitcnt vmcnt(0)" ::: "memory");
  __builtin_amdgcn_s_barrier();

  for (int T = 0; T < NT; ++T) {
    const signed char* Ar = As + (T & 1) * TILE_BYTES;
    v4i a2[8][2];

    // pinned A-read issue: a01(4) | a23(4) | a45(4) | a67(4)
#pragma unroll
    for (int mi = 0; mi < 2; ++mi)
#pragma unroll
      for (int ks = 0; ks < 2; ++ks)
        a2[mi][ks] = *(const v4i*)(Ar + aoff + mi * 2048 + axor[ks]);
    __builtin_amdgcn_sched_barrier(0);
#pragma unroll
    for (int mi = 2; mi < 4; ++mi)
#pragma unroll
      for (int ks = 0; ks < 2; ++ks)
        a2[mi][ks] = *(const v4i*)(Ar + aoff + mi * 2048 + axor[ks]);
    __builtin_amdgcn_sched_barrier(0);
#pragma unroll
    for (int mi = 4; mi < 6; ++mi)
#pragma unroll
      for (int ks = 0; ks < 2; ++ks)
        a2[mi][ks] = *(const v4i*)(Ar + aoff + mi * 2048 + axor[ks]);
    __builtin_amdgcn_sched_barrier(0);
#pragma unroll
    for (int mi = 6; mi < 8; ++mi)
#pragma unroll
      for (int ks = 0; ks < 2; ++ks)
        a2[mi][ks] = *(const v4i*)(Ar + aoff + mi * 2048 + axor[ks]);
    __builtin_amdgcn_sched_barrier(0);

    // stage next A tile into buf^1 (no WAR: reads are from buf)
    if (T + 1 < NT) STAGE_A(T + 1);

    // gate: b(T) landed (bpref(T) are the oldest vmem ops)
    if (T + 1 < NT) VM_GATE(4); else VM_GATE(0);

    // MFMA clusters, counted lgkm gates on A reads, free-run
    LGKM_GATE(12);
    __builtin_amdgcn_s_setprio(1);
    MFMA_PAIR2(0, 1);
    __builtin_amdgcn_s_setprio(0);
    LGKM_GATE(8);
    __builtin_amdgcn_s_setprio(1);
    MFMA_PAIR2(2, 3);
    __builtin_amdgcn_s_setprio(0);
    LGKM_GATE(4);
    __builtin_amdgcn_s_setprio(1);
    MFMA_PAIR2(4, 5);
    __builtin_amdgcn_s_setprio(0);
    LGKM_GATE(0);
    __builtin_amdgcn_s_setprio(1);
    MFMA_PAIR2(6, 7);
    __builtin_amdgcn_s_setprio(0);
    __builtin_amdgcn_sched_barrier(0);

    // prefetch b(T+1) AFTER last b use (in-order issue => WAR-safe, 0 regs)
    if (T + 1 < NT) BPREF(T + 1);
    __builtin_amdgcn_sched_barrier(0);

    // boundary: stage(T+1) drained (bpref(T+1) stays in flight)
    if (T + 1 < NT) {
      asm volatile("s_waitcnt vmcnt(8)" ::: "memory");
    } else {
      asm volatile("s_waitcnt vmcnt(0)" ::: "memory");
    }
    __builtin_amdgcn_s_barrier();
  }

  // epilogue: C/D layout col = lane&15, row = (lane>>4)*4 + reg
  float sbv[4];
#pragma unroll
  for (int nj = 0; nj < 4; ++nj) sbv[nj] = sB[n0 + wn * 64 + nj * 16 + l16];
#pragma unroll
  for (int mi = 0; mi < 8; ++mi) {
#pragma unroll
    for (int r = 0; r < 4; ++r) {
      const int row = m0 + wm * 128 + mi * 16 + lhi * 4 + r;
      const float sav = sA[row];
      float* crow = C + (size_t)row * N + (n0 + wn * 64 + l16);
#pragma unroll
      for (int nj = 0; nj < 4; ++nj)
        crow[nj * 16] = (float)acc[mi][nj][r] * sav * sbv[nj];
    }
  }
}

extern "C" void kernel_launch(void* const* d_in, const int* in_sizes, int n_in,
                              void* d_out, int out_size, void* d_ws, size_t ws_size,
                              hipStream_t stream) {
  const float* A = (const float*)d_in[0];
  const float* B = (const float*)d_in[1];
  float* C = (float*)d_out;
  const int K = K_DIM;
  const int M = in_sizes[0] / K;  // 8192
  const int N = in_sizes[1] / K;  // 4096

  signed char* qA = (signed char*)d_ws;
  signed char* qB = qA + (size_t)M * K;
  float* sA = (float*)(qB + (size_t)N * K);
  float* sB = sA + M;

  quant_rows_kernel<<<M, TPB_Q, 0, stream>>>(A, qA, sA);
  quant_rows_kernel<<<N, TPB_Q, 0, stream>>>(B, qB, sB);

  dim3 grid(N / BN, M / BM);
  gemm_i8_kernel<<<grid, 512, 0, stream>>>(qA, qB, sA, sB, C, M, N, K);
}

// Round 15
// 195.237 us; speedup vs baseline: 1.2375x; 1.2375x over previous
//
#include <hip/hip_runtime.h>
#include <stdint.h>

typedef int v4i __attribute__((ext_vector_type(4)));
typedef int v16i __attribute__((ext_vector_type(16)));

#define K_DIM 4096
#define TPB_Q 256
#define BM 256
#define BN 256
#define BKB 128                     // K-bytes per tile
#define NT (K_DIM / BKB)            // 32 K-tiles
#define TILE_BYTES (256 * BKB)      // 32 KiB per operand tile

__device__ __forceinline__ void load_lds16(const void* g, void* l) {
  __builtin_amdgcn_global_load_lds(
      (const __attribute__((address_space(1))) void*)g,
      (__attribute__((address_space(3))) void*)l, 16, 0, 0);
}

// ---------------- per-row symmetric int8 quant (BW-bound, unchanged) --------
__global__ __launch_bounds__(TPB_Q) void quant_rows_kernel(
    const float* __restrict__ x, signed char* __restrict__ q,
    float* __restrict__ scales) {
  const int row = blockIdx.x;
  const float4* xr = (const float4*)(x + (size_t)row * K_DIM);
  float4 v[4];
  float m = 0.0f;
#pragma unroll
  for (int i = 0; i < 4; ++i) {
    v[i] = xr[threadIdx.x + i * TPB_Q];
    m = fmaxf(m, fmaxf(fmaxf(fabsf(v[i].x), fabsf(v[i].y)),
                       fmaxf(fabsf(v[i].z), fabsf(v[i].w))));
  }
#pragma unroll
  for (int off = 32; off > 0; off >>= 1) m = fmaxf(m, __shfl_down(m, off));
  __shared__ float red[TPB_Q / 64];
  if ((threadIdx.x & 63) == 0) red[threadIdx.x >> 6] = m;
  __syncthreads();
  m = fmaxf(fmaxf(red[0], red[1]), fmaxf(red[2], red[3]));
  const float scale = fmaxf(m / 127.0f, 1e-8f);
  if (threadIdx.x == 0) scales[row] = scale;
  uint32_t* qr = (uint32_t*)(q + (size_t)row * K_DIM);
#pragma unroll
  for (int i = 0; i < 4; ++i) {
    const float4 t = v[i];
    const int a0 = (int)fminf(fmaxf(rintf(t.x / scale), -128.0f), 127.0f);
    const int a1 = (int)fminf(fmaxf(rintf(t.y / scale), -128.0f), 127.0f);
    const int a2 = (int)fminf(fmaxf(rintf(t.z / scale), -128.0f), 127.0f);
    const int a3 = (int)fminf(fmaxf(rintf(t.w / scale), -128.0f), 127.0f);
    const uint32_t p = (uint32_t)(a0 & 255) | ((uint32_t)(a1 & 255) << 8) |
                       ((uint32_t)(a2 & 255) << 16) | ((uint32_t)(a3 & 255) << 24);
    qr[threadIdx.x + i * TPB_Q] = p;
  }
}

// -------- 256x256 i8 GEMM, R8 free-run schedule + 32x32x32 MFMA ------------
// 8 waves (wm 2 x wn 4); per-wave C 128x64 = 4mi x 2nj 32x32 blocks =
// acc[4][2] of i32x16 (128 AGPRs, same as R8).
// Fragments: a[4][4] (mi x kslice, 64 VGPR) + b[2][4] (nj x kslice, 32 VGPR)
// = 96, same budget as R8 (R9/R11 lesson: stay under the 128-arch cap).
// mfma_i32_32x32x32_i8: A/B = 4 VGPR (16B): row/col = lane&31, k =
// (lane>>5)*16 + elem (same pattern as the verified 16x16x64). C/D:
// col = lane&31, row = (reg&3) + 8*(reg>>2) + 4*(lane>>5) [HW-verified].
// LDS: A,B full-tile double buffers (4 x 32 KiB = 128 KiB), rows 128 B =
// 8 chunks, XOR swizzle phys_chunk = logical ^ (row&7); stage dest linear,
// source inverse-swizzled (as R8).
// Per K-tile (free-run, 1 barrier): issue 24 ds_reads in 2 pinned groups
// (b[2][4]+a[0..1][4] = 16 | a[2..3][4] = 8); stage T+1 (8 gload_lds);
// LGKM_GATE(8) -> cluster mi01 (16 MFMA, acc dep distance 4);
// LGKM_GATE(0) -> cluster mi23; vmcnt(0)+s_barrier at boundary.
// XCD swizzle: grid 32r x 16c; XCD k owns rows[8*(k>>1),+8) x cols[8*(k&1),+8).
__global__ __launch_bounds__(512, 2) void gemm_i8_kernel(
    const signed char* __restrict__ qA, const signed char* __restrict__ qB,
    const float* __restrict__ sA, const float* __restrict__ sB,
    float* __restrict__ C, int M, int N, int K) {
  __shared__ __align__(16) signed char As[2 * TILE_BYTES];  // 64 KiB
  __shared__ __align__(16) signed char Bs[2 * TILE_BYTES];  // 64 KiB

  const int tid = threadIdx.x;
  const int wave = tid >> 6, lane = tid & 63;
  const int l32 = lane & 31, l5 = lane >> 5;
  const int wm = wave >> 2, wn = wave & 3;

  // XCD-chunked 2-D swizzle (bijective; 512 blocks, 8 XCDs, o%8 = XCD)
  const int o = blockIdx.x + blockIdx.y * gridDim.x;
  const int xcd = o & 7, slot = o >> 3;
  const int rb = ((xcd >> 1) << 3) + (slot >> 3);  // grid row 0..31
  const int cb = ((xcd & 1) << 3) + (slot & 7);    // grid col 0..15
  const int m0 = rb * BM, n0 = cb * BN;

  const signed char* Abase = qA + (size_t)m0 * K;
  const signed char* Bbase = qB + (size_t)n0 * K;

  // staging: tile = 2048 x 16B chunks; thread d = s*512+tid, s=0..3.
  // dest linear (wave-uniform base + lane*16); source inverse-swizzled.
  int soff[4], sdst[4];
#pragma unroll
  for (int s = 0; s < 4; ++s) {
    const int d = s * 512 + tid;
    const int r = d >> 3;
    const int c = (d & 7) ^ (r & 7);
    soff[s] = r * K + c * 16;
    sdst[s] = s * 8192 + wave * 1024;
  }

#define STAGE_A(T_)                                                         \
  do {                                                                      \
    _Pragma("unroll") for (int s = 0; s < 4; ++s)                           \
        load_lds16(Abase + (size_t)(T_)*BKB + soff[s],                      \
                   As + ((T_)&1) * TILE_BYTES + sdst[s]);                   \
  } while (0)
#define STAGE_B(T_)                                                         \
  do {                                                                      \
    _Pragma("unroll") for (int s = 0; s < 4; ++s)                           \
        load_lds16(Bbase + (size_t)(T_)*BKB + soff[s],                      \
                   Bs + ((T_)&1) * TILE_BYTES + sdst[s]);                   \
  } while (0)

  // fragment ds_read offsets: logical chunk = ks*2 + l5, row&7 = l32&7
  int axor[4];
#pragma unroll
  for (int ks = 0; ks < 4; ++ks)
    axor[ks] = (((ks * 2 + l5) ^ (l32 & 7)) << 4);
  const int aoff = wm * 16384 + l32 * 128;  // + mi*4096 (32 rows)
  const int boff = wn * 8192 + l32 * 128;   // + nj*4096

  const v16i vz16 = {0, 0, 0, 0, 0, 0, 0, 0, 0, 0, 0, 0, 0, 0, 0, 0};
  v16i acc[4][2];
#pragma unroll
  for (int i = 0; i < 4; ++i)
#pragma unroll
    for (int j = 0; j < 2; ++j) acc[i][j] = vz16;

  // prologue: stage tile 0, drain, sync.
  STAGE_A(0); STAGE_B(0);
  asm volatile("s_waitcnt vmcnt(0)" ::: "memory");
  __builtin_amdgcn_s_barrier();

// 16 MFMA: 2 mi-rows x 2 nj x 4 kslices; acc reuse at distance 4
#define MFMA_CLUSTER(p0_, p1_)                                               \
  do {                                                                       \
    _Pragma("unroll") for (int ks = 0; ks < 4; ++ks) {                       \
      acc[p0_][0] = __builtin_amdgcn_mfma_i32_32x32x32_i8(                   \
          a[p0_][ks], b[0][ks], acc[p0_][0], 0, 0, 0);                       \
      acc[p0_][1] = __builtin_amdgcn_mfma_i32_32x32x32_i8(                   \
          a[p0_][ks], b[1][ks], acc[p0_][1], 0, 0, 0);                       \
      acc[p1_][0] = __builtin_amdgcn_mfma_i32_32x32x32_i8(                   \
          a[p1_][ks], b[0][ks], acc[p1_][0], 0, 0, 0);                       \
      acc[p1_][1] = __builtin_amdgcn_mfma_i32_32x32x32_i8(                   \
          a[p1_][ks], b[1][ks], acc[p1_][1], 0, 0, 0);                       \
    }                                                                        \
  } while (0)

#define LGKM_GATE(n_)                                       \
  do {                                                      \
    asm volatile("s_waitcnt lgkmcnt(" #n_ ")" ::: "memory");\
    __builtin_amdgcn_sched_barrier(0);                      \
  } while (0)

  for (int T = 0; T < NT; ++T) {
    const signed char* Ar = As + (T & 1) * TILE_BYTES;
    const signed char* Br = Bs + (T & 1) * TILE_BYTES;
    v4i a[4][4], b[2][4];

    // pinned read issue: group1 = b[2][4] + a[0..1][4] (16), group2 = a[2..3][4] (8)
#pragma unroll
    for (int nj = 0; nj < 2; ++nj)
#pragma unroll
      for (int ks = 0; ks < 4; ++ks)
        b[nj][ks] = *(const v4i*)(Br + boff + nj * 4096 + axor[ks]);
#pragma unroll
    for (int mi = 0; mi < 2; ++mi)
#pragma unroll
      for (int ks = 0; ks < 4; ++ks)
        a[mi][ks] = *(const v4i*)(Ar + aoff + mi * 4096 + axor[ks]);
    __builtin_amdgcn_sched_barrier(0);
#pragma unroll
    for (int mi = 2; mi < 4; ++mi)
#pragma unroll
      for (int ks = 0; ks < 4; ++ks)
        a[mi][ks] = *(const v4i*)(Ar + aoff + mi * 4096 + axor[ks]);
    __builtin_amdgcn_sched_barrier(0);

    // stage next tile into buf^1 (no WAR: reads are from buf)
    if (T + 1 < NT) { STAGE_A(T + 1); STAGE_B(T + 1); }

    // MFMA clusters, counted lgkm gates, free-run (no intra-tile barrier)
    LGKM_GATE(8);
    __builtin_amdgcn_s_setprio(1);
    MFMA_CLUSTER(0, 1);
    __builtin_amdgcn_s_setprio(0);
    LGKM_GATE(0);
    __builtin_amdgcn_s_setprio(1);
    MFMA_CLUSTER(2, 3);
    __builtin_amdgcn_s_setprio(0);

    // boundary: own stage landed (covered by MFMA span), cross-wave fence
    asm volatile("s_waitcnt vmcnt(0)" ::: "memory");
    __builtin_amdgcn_s_barrier();
  }

  // epilogue: 32x32 C/D layout: col = lane&31, row = (r&3)+8*(r>>2)+4*(lane>>5)
  float sbv[2];
#pragma unroll
  for (int nj = 0; nj < 2; ++nj) sbv[nj] = sB[n0 + wn * 64 + nj * 32 + l32];
#pragma unroll
  for (int mi = 0; mi < 4; ++mi) {
#pragma unroll
    for (int r = 0; r < 16; ++r) {
      const int row = m0 + wm * 128 + mi * 32 + (r & 3) + 8 * (r >> 2) + 4 * l5;
      const float sav = sA[row];
      float* crow = C + (size_t)row * N + (n0 + wn * 64 + l32);
#pragma unroll
      for (int nj = 0; nj < 2; ++nj)
        crow[nj * 32] = (float)acc[mi][nj][r] * sav * sbv[nj];
    }
  }
}

extern "C" void kernel_launch(void* const* d_in, const int* in_sizes, int n_in,
                              void* d_out, int out_size, void* d_ws, size_t ws_size,
                              hipStream_t stream) {
  const float* A = (const float*)d_in[0];
  const float* B = (const float*)d_in[1];
  float* C = (float*)d_out;
  const int K = K_DIM;
  const int M = in_sizes[0] / K;  // 8192
  const int N = in_sizes[1] / K;  // 4096

  signed char* qA = (signed char*)d_ws;
  signed char* qB = qA + (size_t)M * K;
  float* sA = (float*)(qB + (size_t)N * K);
  float* sB = sA + M;

  quant_rows_kernel<<<M, TPB_Q, 0, stream>>>(A, qA, sA);
  quant_rows_kernel<<<N, TPB_Q, 0, stream>>>(B, qB, sB);

  dim3 grid(N / BN, M / BM);
  gemm_i8_kernel<<<grid, 512, 0, stream>>>(qA, qB, sA, sB, C, M, N, K);
}